// Round 10
// baseline (612.469 us; speedup 1.0000x reference)
//
#include <hip/hip_runtime.h>

// SimpleMACELayer on gfx950 — round 13: Sf streaming (spill kill) + setprio on G2.
//
//   F[h][o2][kk]   = sum_o tpw[p(kk)][h][o] * W_lin[o2][o*16 + kg(kk)]  (f16, kk pad 112, ws)
//   CGd[kk][i][j]  = cg[i][j][kg(kk)] masked to i in [b1,b1+ni), j in [b2,b2+nj)  (f16, ws)
//   A_e[kk][i]     = sum_j CGd[kk][i][j] * Y_e[j]          (dense MFMA 16x16x16f16)
//   U[e][h][kk]    = sum_i A_e[kk][i] * src[e][h][i]       (GEMM-1, per edge)
//   out[dst(e),:] += sum_{h,kk} U[e][h][kk] * F[h][:][kk]  (GEMM-2, 16x16x32 / 16 tail)
//
// Round-12 post-mortem: de-overlap worked (spill 62->21MB, 397->371us) but VGPR still
// pinned at 128: Sf[8][4] (64 regs, whole-kernel live) + bF[4][4] (64) = 128 alone.
// Fix: STREAM Sf per phase — slices are hg-disjoint, so keep only SfC[8] f16 (16 regs)
// + SfN4[8] float4 in flight (32 regs), issued mid-G2 (32 bF regs already dead),
// cvt'd at next phase start. nf re-read x4 is L3-resident (80MB < 256MB cache).
// Peak ~112 regs -> no spill at 2 blocks/CU. Plus T5 setprio(1) around G2 MFMAs
// (2 independent blocks/CU = role diversity, the m191 +4-7% regime; R9/R10's test
// of it was spill-confounded).
// Tripwires: WRITE must drop to ~25MB (else Sf theory wrong -> revert+ablate);
// VGPR off the 128 pin; occ ~22.

#define NKK 99
#define NKPAD 112
#define EPB 32
#define THREADS 256
#define SA_ESTR 516   // [e][kk32][i16] f16, e-stride (258 dw)
#define SU_HSTR 40    // [e][h'16][kk32] f16, h-stride (20 dw)
#define SU_ESTR 648   // e-stride (324 dw)
#define RED_ESTR 68   // fp32 red row stride

typedef _Float16 f16;
typedef f16 f16x4 __attribute__((ext_vector_type(4)));
typedef f16 f16x8 __attribute__((ext_vector_type(8)));
typedef float f32x4 __attribute__((ext_vector_type(4)));

__device__ __constant__ short PK_P[NKK] = {
  0, 1,1,1, 2,2,2,2,2, 3,3,3,3,3,3,3, 4,4,4, 5, 6,6,6,6,6, 7,7,7,
  8,8,8,8,8,8,8, 9,9,9,9,9, 10,10,10,10,10, 11,11,11, 12,12,12,12,12,12,12,
  13, 14,14,14,14,14, 15,15,15, 16,16,16,16,16,16,16, 17,17,17,17,17,17,17,
  18,18,18,18,18, 19,19,19, 20,20,20,20,20,20,20, 21, 22,22,22,22,22};
__device__ __constant__ short KK_L1[NKK] = {
  0, 0,0,0, 0,0,0,0,0, 0,0,0,0,0,0,0, 1,1,1, 1, 1,1,1,1,1, 1,1,1,
  1,1,1,1,1,1,1, 1,1,1,1,1, 2,2,2,2,2, 2,2,2, 2,2,2,2,2,2,2,
  2, 2,2,2,2,2, 2,2,2, 2,2,2,2,2,2,2, 3,3,3,3,3,3,3,
  3,3,3,3,3, 3,3,3, 3,3,3,3,3,3,3, 3, 3,3,3,3,3};
__device__ __constant__ short KK_L2[NKK] = {
  0, 1,1,1, 2,2,2,2,2, 3,3,3,3,3,3,3, 0,0,0, 1, 1,1,1,1,1, 2,2,2,
  2,2,2,2,2,2,2, 3,3,3,3,3, 0,0,0,0,0, 1,1,1, 1,1,1,1,1,1,1,
  2, 2,2,2,2,2, 3,3,3, 3,3,3,3,3,3,3, 0,0,0,0,0,0,0,
  1,1,1,1,1, 2,2,2, 2,2,2,2,2,2,2, 3, 3,3,3,3,3};
__device__ __constant__ short KK_KG[NKK] = {
  0, 1,2,3, 4,5,6,7,8, 9,10,11,12,13,14,15, 1,2,3, 0, 4,5,6,7,8, 1,2,3,
  9,10,11,12,13,14,15, 4,5,6,7,8, 4,5,6,7,8, 1,2,3, 9,10,11,12,13,14,15,
  0, 4,5,6,7,8, 1,2,3, 9,10,11,12,13,14,15, 9,10,11,12,13,14,15,
  4,5,6,7,8, 1,2,3, 9,10,11,12,13,14,15, 0, 4,5,6,7,8};

// ---------------- F[h][o2][kk] = sum_o tpw[p][h][o] * wlin[o2][o*16+kg]  (+ fused CGd)
// grid = NKPAD; blocks kk>=NKK zero their F column (keeps NaN garbage out of tail MFMAs).
__global__ __launch_bounds__(256) void compute_F(const float* __restrict__ tpw,
                                                 const float* __restrict__ wlin,
                                                 const float* __restrict__ cg,
                                                 f16* __restrict__ F,
                                                 f16* __restrict__ CGd) {
  int kk = blockIdx.x;
  int tid = threadIdx.x;

  // --- fused CGd slice for this kk (zero for kk >= NKK / outside the l1/l2 window)
  {
    int i = tid >> 4, j = tid & 15;
    f16 v = (f16)0.f;
    if (kk < NKK) {
      int l1 = KK_L1[kk], l2 = KK_L2[kk], kg = KK_KG[kk];
      int b1 = l1 * l1, b2 = l2 * l2;
      if (i >= b1 && i < b1 + 2 * l1 + 1 && j >= b2 && j < b2 + 2 * l2 + 1)
        v = (f16)cg[(i * 16 + j) * 16 + kg];
    }
    CGd[kk * 256 + tid] = v;
  }

  if (kk >= NKK) {
    for (int r = tid; r < 64 * 64; r += 256) F[(size_t)r * NKPAD + kk] = (f16)0.f;
    return;
  }
  int p  = PK_P[kk];
  int c3 = KK_KG[kk];

  __shared__ float wl[64][65];
  for (int idx = tid; idx < 64 * 64; idx += 256) {
    int o2 = idx >> 6, o = idx & 63;
    wl[o2][o] = wlin[o2 * 1024 + o * 16 + c3];
  }
  __syncthreads();

  int h = tid & 63, og = tid >> 6;
  float acc[16];
#pragma unroll
  for (int m = 0; m < 16; ++m) acc[m] = 0.f;
  const float* tw = tpw + (p * 64 + h) * 64;
  for (int o = 0; o < 64; ++o) {
    float w = tw[o];
#pragma unroll
    for (int m = 0; m < 16; ++m) acc[m] += w * wl[og * 16 + m][o];
  }
#pragma unroll
  for (int m = 0; m < 16; ++m)
    F[(size_t)(h * 64 + og * 16 + m) * NKPAD + kk] = (f16)acc[m];
}

// ---------------- out init
__global__ void init_out(float* __restrict__ out, const float* __restrict__ b, int n) {
  int i = blockIdx.x * 256 + threadIdx.x;
  if (i < n) out[i] = b[i & 63];
}

// ---------------- main edge kernel (32 edges/block, 75.8KB LDS -> 2 blocks/CU)
__global__ __launch_bounds__(THREADS, 2) void edge_kernel(
    const float* __restrict__ nf, const float* __restrict__ ev,
    const int* __restrict__ eidx, const f16* __restrict__ CGd,
    const f16* __restrict__ F, float* __restrict__ out, int NE) {

  __shared__ f16 sYh[EPB * 16];
  __shared__ int sSrcA[EPB];
  __shared__ int sDst[EPB];
  __shared__ f16 sA[EPB * SA_ESTR];   // 33.0KB
  __shared__ f16 sU[EPB * SU_ESTR];   // 41.5KB ; reused as fp32 red[4][32][68] (34.8KB)

  int tid = threadIdx.x;
  int wave = tid >> 6, lane = tid & 63;
  int lm = lane & 15, lq = lane >> 4;

  // --- phase 0: edge meta + spherical harmonics (f16)
  if (tid < EPB) {
    int eg = blockIdx.x * EPB + tid;
    int sa = 0, da = -1;
    float x = 0.f, y = 0.f, z = 0.f;
    if (eg < NE) {
      sa = eidx[eg];
      da = eidx[NE + eg];
      x = ev[3 * eg + 0]; y = ev[3 * eg + 1]; z = ev[3 * eg + 2];
    }
    sSrcA[tid] = sa;
    sDst[tid] = da;
    float x2 = x * x, y2 = y * y, z2 = z * z;
    float Y[16];
    Y[0]  = 0.28209479177387814f;
    Y[1]  = 0.4886025119029199f * y;
    Y[2]  = 0.4886025119029199f * z;
    Y[3]  = 0.4886025119029199f * x;
    Y[4]  = 1.0925484305920792f * x * y;
    Y[5]  = 1.0925484305920792f * y * z;
    Y[6]  = 0.31539156525252005f * (3.0f * z2 - 1.0f);
    Y[7]  = 1.0925484305920792f * x * z;
    Y[8]  = 0.5462742152960396f * (x2 - y2);
    Y[9]  = 0.5900435899266435f * y * (3.0f * x2 - y2);
    Y[10] = 2.890611442640554f * x * y * z;
    Y[11] = 0.4570457994644658f * y * (5.0f * z2 - 1.0f);
    Y[12] = 0.3731763325901154f * z * (5.0f * z2 - 3.0f);
    Y[13] = 0.4570457994644658f * x * (5.0f * z2 - 1.0f);
    Y[14] = 1.445305721320277f  * z * (x2 - y2);
    Y[15] = 0.5900435899266435f * x * (x2 - 3.0f * y2);
#pragma unroll
    for (int j = 0; j < 16; ++j) sYh[tid * 16 + j] = (f16)Y[j];
  }
  __syncthreads();

  // --- per-wave edge metadata (8 edges/wave): atom indices in 8 VGPRs
  int ebase = wave * 8;
  int srcAtom[8];
#pragma unroll
  for (int ei = 0; ei < 8; ++ei) srcAtom[ei] = sSrcA[ebase + ei];

  // --- Sf streaming state: SfN4 = next phase's slice (float4, in flight);
  //     converted to SfC (f16x4) at each phase start. Slice for phase with
  //     index hg: src[e][h=hg*16+lm][i=lq*4..+3]. Prologue primes hg=0.
  float4 SfN4[8];
#pragma unroll
  for (int ei = 0; ei < 8; ++ei)
    SfN4[ei] = ((const float4*)nf)[(size_t)srcAtom[ei] * 256 + (0 * 16 + lm) * 4 + lq];

  // B-frags for A-build: Y[e=lm][j] and Y[e=16+lm][j]
  f16x4 bY0 = *(const f16x4*)&sYh[lm * 16 + lq * 4];
  f16x4 bY1 = *(const f16x4*)&sYh[(16 + lm) * 16 + lq * 4];

  f32x4 acc[2][4];
#pragma unroll
  for (int et = 0; et < 2; ++et)
#pragma unroll
    for (int ot = 0; ot < 4; ++ot) acc[et][ot] = f32x4{0.f, 0.f, 0.f, 0.f};

  // A-build: NT_ tiles per wave starting at global kk = kkb_, both e-halves; D[row=i][col=e]
#define A_BUILD(kkb_, NT_)                                                             \
  {                                                                                    \
    _Pragma("unroll")                                                                  \
    for (int tl = 0; tl < (NT_); ++tl) {                                               \
      int t = wave * (NT_) + tl;                                                       \
      f16x4 aCG = *(const f16x4*)&CGd[(size_t)((kkb_) + t) * 256 + lm * 16 + lq * 4];  \
      f32x4 d0 = __builtin_amdgcn_mfma_f32_16x16x16f16(aCG, bY0, f32x4{0.f, 0.f, 0.f, 0.f}, 0, 0, 0); \
      f32x4 d1 = __builtin_amdgcn_mfma_f32_16x16x16f16(aCG, bY1, f32x4{0.f, 0.f, 0.f, 0.f}, 0, 0, 0); \
      f16x4 dh0 = {(f16)d0[0], (f16)d0[1], (f16)d0[2], (f16)d0[3]};                    \
      f16x4 dh1 = {(f16)d1[0], (f16)d1[1], (f16)d1[2], (f16)d1[3]};                    \
      *(f16x4*)&sA[lm * SA_ESTR + t * 16 + lq * 4] = dh0;        /* [e=lm   ][kk=t][i] */ \
      *(f16x4*)&sA[(16 + lm) * SA_ESTR + t * 16 + lq * 4] = dh1; /* [e=16+lm][kk=t][i] */ \
    }                                                                                  \
  }

  A_BUILD(0, 8);
  __syncthreads();

  // ================= full 32-kk tiles: kg = 0,1,2 =================
  for (int kg = 0; kg < 3; ++kg) {
#pragma unroll
    for (int hg = 0; hg < 4; ++hg) {
      // --- phase start: finalize this phase's streamed Sf (vmcnt wait lands here,
      //     ~a full G2-half + barrier after issue). float4 regs die at the cvt.
      f16x4 SfC[8];
#pragma unroll
      for (int ei = 0; ei < 8; ++ei) {
        float4 v = SfN4[ei];
        SfC[ei] = f16x4{(f16)v.x, (f16)v.y, (f16)v.z, (f16)v.w};
      }

      // --- FULL F prefetch for this (kg,hg): all 16 loads issued before GEMM-1
      //     so L2 latency hides under GEMM-1's MFMA+LDS work (champion pattern).
      f16x8 bF[4][4];
#pragma unroll
      for (int hi = 0; hi < 4; ++hi) {
        const f16* Fb = F + (size_t)(hg * 16 + wave + 4 * hi) * 64 * NKPAD + kg * 32 + lq * 8;
#pragma unroll
        for (int ot = 0; ot < 4; ++ot)
          bF[hi][ot] = *(const f16x8*)&Fb[(size_t)(ot * 16 + lm) * NKPAD];
      }

      // --- GEMM-1: U[kk32][h'16] per edge; A=sA rows kkloc, B=SfC
#pragma unroll
      for (int ei = 0; ei < 8; ++ei) {
        int e = ebase + ei;
        f16x4 bS = SfC[ei];
#pragma unroll
        for (int kt = 0; kt < 2; ++kt) {
          f16x4 aA = *(const f16x4*)&sA[e * SA_ESTR + (kt * 16 + lm) * 16 + lq * 4];
          f32x4 d = __builtin_amdgcn_mfma_f32_16x16x16f16(aA, bS, f32x4{0.f, 0.f, 0.f, 0.f}, 0, 0, 0);
          f16x4 dh = {(f16)d[0], (f16)d[1], (f16)d[2], (f16)d[3]};
          *(f16x4*)&sU[e * SU_ESTR + lm * SU_HSTR + kt * 16 + lq * 4] = dh;  // [e][h'=lm][kk]
        }
      }
      __syncthreads();

      // --- GEMM-2 first half (hi 0,1): acc += U * F ; setprio favors MFMA wave
      __builtin_amdgcn_s_setprio(1);
#pragma unroll
      for (int hi = 0; hi < 2; ++hi) {
        int hl = wave + 4 * hi;
#pragma unroll
        for (int et = 0; et < 2; ++et) {
          f16x8 a0 = *(const f16x8*)&sU[(size_t)(et * 16 + lm) * SU_ESTR + hl * SU_HSTR + lq * 8];
#pragma unroll
          for (int ot = 0; ot < 4; ++ot)
            acc[et][ot] = __builtin_amdgcn_mfma_f32_16x16x32_f16(a0, bF[hi][ot], acc[et][ot], 0, 0, 0);
        }
      }
      __builtin_amdgcn_s_setprio(0);

      // --- stream next phase's Sf slice (hi 0,1's 32 bF regs are dead now; these
      //     loads fly across the end barrier and are waited at next phase's cvt)
      {
        int nhg = (hg + 1) & 3;   // kg,3 -> next kg's (or tail's) hg=0
#pragma unroll
        for (int ei = 0; ei < 8; ++ei)
          SfN4[ei] = ((const float4*)nf)[(size_t)srcAtom[ei] * 256 + (nhg * 16 + lm) * 4 + lq];
      }

      // --- GEMM-2 second half (hi 2,3)
      __builtin_amdgcn_s_setprio(1);
#pragma unroll
      for (int hi = 2; hi < 4; ++hi) {
        int hl = wave + 4 * hi;
#pragma unroll
        for (int et = 0; et < 2; ++et) {
          f16x8 a0 = *(const f16x8*)&sU[(size_t)(et * 16 + lm) * SU_ESTR + hl * SU_HSTR + lq * 8];
#pragma unroll
          for (int ot = 0; ot < 4; ++ot)
            acc[et][ot] = __builtin_amdgcn_mfma_f32_16x16x32_f16(a0, bF[hi][ot], acc[et][ot], 0, 0, 0);
        }
      }
      __builtin_amdgcn_s_setprio(0);

      // --- A-build for the next kk-tile, AFTER G2 so the 64 bF VGPRs are dead
      //     before aCG/d0/d1 go live. Race-equivalent (see R12 note). The
      //     sched_barrier(0) stops the scheduler hoisting aCG loads under bF.
      if (hg == 3) {
        __builtin_amdgcn_sched_barrier(0);
        if (kg < 2) A_BUILD((kg + 1) * 32, 8)
        else        A_BUILD(96, 4)          // tail tile: 16 kk
      }
      __syncthreads();
    }
  }

  // ================= tail 16-kk tile: kk 96..111 (16x16x16 MFMA) =================
#pragma unroll
  for (int hg = 0; hg < 4; ++hg) {
    // phase start: finalize streamed Sf
    f16x4 SfC[8];
#pragma unroll
    for (int ei = 0; ei < 8; ++ei) {
      float4 v = SfN4[ei];
      SfC[ei] = f16x4{(f16)v.x, (f16)v.y, (f16)v.z, (f16)v.w};
    }

    f16x4 bFt[4][4];
#pragma unroll
    for (int hi = 0; hi < 4; ++hi) {
      const f16* Fb = F + (size_t)(hg * 16 + wave + 4 * hi) * 64 * NKPAD + 96 + lq * 4;
#pragma unroll
      for (int ot = 0; ot < 4; ++ot)
        bFt[hi][ot] = *(const f16x4*)&Fb[(size_t)(ot * 16 + lm) * NKPAD];
    }

    // GEMM-1 tail: single 16-kk row block
#pragma unroll
    for (int ei = 0; ei < 8; ++ei) {
      int e = ebase + ei;
      f16x4 bS = SfC[ei];
      f16x4 aA = *(const f16x4*)&sA[e * SA_ESTR + lm * 16 + lq * 4];
      f32x4 d = __builtin_amdgcn_mfma_f32_16x16x16f16(aA, bS, f32x4{0.f, 0.f, 0.f, 0.f}, 0, 0, 0);
      f16x4 dh = {(f16)d[0], (f16)d[1], (f16)d[2], (f16)d[3]};
      *(f16x4*)&sU[e * SU_ESTR + lm * SU_HSTR + lq * 4] = dh;
    }
    __syncthreads();

    // GEMM-2 tail: K = 16 (split; stream next slice between halves)
    __builtin_amdgcn_s_setprio(1);
#pragma unroll
    for (int hi = 0; hi < 2; ++hi) {
      int hl = wave + 4 * hi;
#pragma unroll
      for (int et = 0; et < 2; ++et) {
        f16x4 a0 = *(const f16x4*)&sU[(size_t)(et * 16 + lm) * SU_ESTR + hl * SU_HSTR + lq * 4];
#pragma unroll
        for (int ot = 0; ot < 4; ++ot)
          acc[et][ot] = __builtin_amdgcn_mfma_f32_16x16x16f16(a0, bFt[hi][ot], acc[et][ot], 0, 0, 0);
      }
    }
    __builtin_amdgcn_s_setprio(0);

    if (hg < 3) {
      int nhg = hg + 1;
#pragma unroll
      for (int ei = 0; ei < 8; ++ei)
        SfN4[ei] = ((const float4*)nf)[(size_t)srcAtom[ei] * 256 + (nhg * 16 + lm) * 4 + lq];
    }

    __builtin_amdgcn_s_setprio(1);
#pragma unroll
    for (int hi = 2; hi < 4; ++hi) {
      int hl = wave + 4 * hi;
#pragma unroll
      for (int et = 0; et < 2; ++et) {
        f16x4 a0 = *(const f16x4*)&sU[(size_t)(et * 16 + lm) * SU_ESTR + hl * SU_HSTR + lq * 4];
#pragma unroll
        for (int ot = 0; ot < 4; ++ot)
          acc[et][ot] = __builtin_amdgcn_mfma_f32_16x16x16f16(a0, bFt[hi][ot], acc[et][ot], 0, 0, 0);
      }
    }
    __builtin_amdgcn_s_setprio(0);
    __syncthreads();
  }

  // --- cross-wave reduction: red[wave][e][o2] (stride 68)
  float* red = (float*)sU;
#pragma unroll
  for (int et = 0; et < 2; ++et)
#pragma unroll
    for (int ot = 0; ot < 4; ++ot)
#pragma unroll
      for (int r = 0; r < 4; ++r) {
        int e = et * 16 + lq * 4 + r;    // D row
        int o2 = ot * 16 + lm;           // D col
        red[(wave * EPB + e) * RED_ESTR + o2] = acc[et][ot][r];
      }
  __syncthreads();

#pragma unroll
  for (int rep = 0; rep < 8; ++rep) {
    int idx = tid + rep * 256;           // 0..2047 = e*64+o2 ; e wave-uniform
    int e = idx >> 6, o2 = idx & 63;
    float s = red[(0 * EPB + e) * RED_ESTR + o2]
            + red[(1 * EPB + e) * RED_ESTR + o2]
            + red[(2 * EPB + e) * RED_ESTR + o2]
            + red[(3 * EPB + e) * RED_ESTR + o2];
    int da = sDst[e];
    if (da >= 0) unsafeAtomicAdd(out + (size_t)da * 64 + o2, s);
  }
}

extern "C" void kernel_launch(void* const* d_in, const int* in_sizes, int n_in,
                              void* d_out, int out_size, void* d_ws, size_t ws_size,
                              hipStream_t stream) {
  const float* nf   = (const float*)d_in[0];  // [NA,64,16]
  const float* ev   = (const float*)d_in[1];  // [NE,3]
  const int*   eidx = (const int*)d_in[2];    // [2,NE]
  const float* cg   = (const float*)d_in[3];  // [16,16,16]
  const float* tpw  = (const float*)d_in[4];  // [23,64,64]
  const float* wlin = (const float*)d_in[5];  // [64,1024]
  const float* blin = (const float*)d_in[6];  // [64]
  float* out = (float*)d_out;                 // [NA,64]

  int NA = in_sizes[0] / 1024;
  int NE = in_sizes[1] / 3;
  f16* F   = (f16*)d_ws;                                         // 64*64*112*2 = 896 KB
  f16* CGd = (f16*)((char*)d_ws + (size_t)64 * 64 * NKPAD * 2);  // 112*256*2 = 56 KB

  compute_F<<<NKPAD, 256, 0, stream>>>(tpw, wlin, cg, F, CGd);   // fused F + CGd (+pad zero)
  init_out<<<(NA * 64 + 255) / 256, 256, 0, stream>>>(out, blin, NA * 64);
  edge_kernel<<<(NE + EPB - 1) / EPB, THREADS, 0, stream>>>(nf, ev, eidx, CGd, F, out, NE);
}

// Round 11
// 432.836 us; speedup vs baseline: 1.4150x; 1.4150x over previous
//
#include <hip/hip_runtime.h>

// SimpleMACELayer on gfx950 — round 14: R12 + bF prefetch split 8+8 (arch-pressure fix).
//
//   F[h][o2][kk]   = sum_o tpw[p(kk)][h][o] * W_lin[o2][o*16 + kg(kk)]  (f16, kk pad 112, ws)
//   CGd[kk][i][j]  = cg[i][j][kg(kk)] masked to i in [b1,b1+ni), j in [b2,b2+nj)  (f16, ws)
//   A_e[kk][i]     = sum_j CGd[kk][i][j] * Y_e[j]          (dense MFMA 16x16x16f16)
//   U[e][h][kk]    = sum_i A_e[kk][i] * src[e][h][i]       (GEMM-1, per edge)
//   out[dst(e),:] += sum_{h,kk} U[e][h][kk] * F[h][:][kk]  (GEMM-2, 16x16x32 / 16 tail)
//
// Round-13 post-mortem: Sf streaming FAILED tripwire (WRITE 197MB, FETCH +296MB, 518us)
// — SfN4 state lives ACROSS a barrier, raising peak pressure; nf re-reads hit HBM.
// Reverted to R12 (371us champion). Register model: (256,2) => ~256 unified budget
// split 128 arch + 128 acc; arch demand Sf(64)+bF(64)+temps ~140 => 21MB spill.
// This round shrinks the bF term instead: split prefetch 8+8. bFa(hi0,1) before G1
// (covered by G1 — champion pattern); bFb(hi2,3) issued right after mid-barrier,
// consumed in G2 second half (covered by G2 first half: 4 ds_read_b128 + 16 MFMA
// ~200-300cy ~ L2 latency; NOT R7's 40cy-cover failure). No cross-barrier reg state.
// Peak arch ~112 < 128. Single variable vs R12.
// Tripwires: WRITE -> ~25-30MB (else stop touching registers); edge <= 371.

#define NKK 99
#define NKPAD 112
#define EPB 32
#define THREADS 256
#define SA_ESTR 516   // [e][kk32][i16] f16, e-stride (258 dw)
#define SU_HSTR 40    // [e][h'16][kk32] f16, h-stride (20 dw)
#define SU_ESTR 648   // e-stride (324 dw)
#define RED_ESTR 68   // fp32 red row stride

typedef _Float16 f16;
typedef f16 f16x4 __attribute__((ext_vector_type(4)));
typedef f16 f16x8 __attribute__((ext_vector_type(8)));
typedef float f32x4 __attribute__((ext_vector_type(4)));

__device__ __constant__ short PK_P[NKK] = {
  0, 1,1,1, 2,2,2,2,2, 3,3,3,3,3,3,3, 4,4,4, 5, 6,6,6,6,6, 7,7,7,
  8,8,8,8,8,8,8, 9,9,9,9,9, 10,10,10,10,10, 11,11,11, 12,12,12,12,12,12,12,
  13, 14,14,14,14,14, 15,15,15, 16,16,16,16,16,16,16, 17,17,17,17,17,17,17,
  18,18,18,18,18, 19,19,19, 20,20,20,20,20,20,20, 21, 22,22,22,22,22};
__device__ __constant__ short KK_L1[NKK] = {
  0, 0,0,0, 0,0,0,0,0, 0,0,0,0,0,0,0, 1,1,1, 1, 1,1,1,1,1, 1,1,1,
  1,1,1,1,1,1,1, 1,1,1,1,1, 2,2,2,2,2, 2,2,2, 2,2,2,2,2,2,2,
  2, 2,2,2,2,2, 2,2,2, 2,2,2,2,2,2,2, 3,3,3,3,3,3,3,
  3,3,3,3,3, 3,3,3, 3,3,3,3,3,3,3, 3, 3,3,3,3,3};
__device__ __constant__ short KK_L2[NKK] = {
  0, 1,1,1, 2,2,2,2,2, 3,3,3,3,3,3,3, 0,0,0, 1, 1,1,1,1,1, 2,2,2,
  2,2,2,2,2,2,2, 3,3,3,3,3, 0,0,0,0,0, 1,1,1, 1,1,1,1,1,1,1,
  2, 2,2,2,2,2, 3,3,3, 3,3,3,3,3,3,3, 0,0,0,0,0,0,0,
  1,1,1,1,1, 2,2,2, 2,2,2,2,2,2,2, 3, 3,3,3,3,3};
__device__ __constant__ short KK_KG[NKK] = {
  0, 1,2,3, 4,5,6,7,8, 9,10,11,12,13,14,15, 1,2,3, 0, 4,5,6,7,8, 1,2,3,
  9,10,11,12,13,14,15, 4,5,6,7,8, 4,5,6,7,8, 1,2,3, 9,10,11,12,13,14,15,
  0, 4,5,6,7,8, 1,2,3, 9,10,11,12,13,14,15, 9,10,11,12,13,14,15,
  4,5,6,7,8, 1,2,3, 9,10,11,12,13,14,15, 0, 4,5,6,7,8};

// ---------------- F[h][o2][kk] = sum_o tpw[p][h][o] * wlin[o2][o*16+kg]  (+ fused CGd)
// grid = NKPAD; blocks kk>=NKK zero their F column (keeps NaN garbage out of tail MFMAs).
__global__ __launch_bounds__(256) void compute_F(const float* __restrict__ tpw,
                                                 const float* __restrict__ wlin,
                                                 const float* __restrict__ cg,
                                                 f16* __restrict__ F,
                                                 f16* __restrict__ CGd) {
  int kk = blockIdx.x;
  int tid = threadIdx.x;

  // --- fused CGd slice for this kk (zero for kk >= NKK / outside the l1/l2 window)
  {
    int i = tid >> 4, j = tid & 15;
    f16 v = (f16)0.f;
    if (kk < NKK) {
      int l1 = KK_L1[kk], l2 = KK_L2[kk], kg = KK_KG[kk];
      int b1 = l1 * l1, b2 = l2 * l2;
      if (i >= b1 && i < b1 + 2 * l1 + 1 && j >= b2 && j < b2 + 2 * l2 + 1)
        v = (f16)cg[(i * 16 + j) * 16 + kg];
    }
    CGd[kk * 256 + tid] = v;
  }

  if (kk >= NKK) {
    for (int r = tid; r < 64 * 64; r += 256) F[(size_t)r * NKPAD + kk] = (f16)0.f;
    return;
  }
  int p  = PK_P[kk];
  int c3 = KK_KG[kk];

  __shared__ float wl[64][65];
  for (int idx = tid; idx < 64 * 64; idx += 256) {
    int o2 = idx >> 6, o = idx & 63;
    wl[o2][o] = wlin[o2 * 1024 + o * 16 + c3];
  }
  __syncthreads();

  int h = tid & 63, og = tid >> 6;
  float acc[16];
#pragma unroll
  for (int m = 0; m < 16; ++m) acc[m] = 0.f;
  const float* tw = tpw + (p * 64 + h) * 64;
  for (int o = 0; o < 64; ++o) {
    float w = tw[o];
#pragma unroll
    for (int m = 0; m < 16; ++m) acc[m] += w * wl[og * 16 + m][o];
  }
#pragma unroll
  for (int m = 0; m < 16; ++m)
    F[(size_t)(h * 64 + og * 16 + m) * NKPAD + kk] = (f16)acc[m];
}

// ---------------- out init
__global__ void init_out(float* __restrict__ out, const float* __restrict__ b, int n) {
  int i = blockIdx.x * 256 + threadIdx.x;
  if (i < n) out[i] = b[i & 63];
}

// ---------------- main edge kernel (32 edges/block, 75.8KB LDS -> 2 blocks/CU)
__global__ __launch_bounds__(THREADS, 2) void edge_kernel(
    const float* __restrict__ nf, const float* __restrict__ ev,
    const int* __restrict__ eidx, const f16* __restrict__ CGd,
    const f16* __restrict__ F, float* __restrict__ out, int NE) {

  __shared__ f16 sYh[EPB * 16];
  __shared__ int sSrcA[EPB];
  __shared__ int sDst[EPB];
  __shared__ f16 sA[EPB * SA_ESTR];   // 33.0KB
  __shared__ f16 sU[EPB * SU_ESTR];   // 41.5KB ; reused as fp32 red[4][32][68] (34.8KB)

  int tid = threadIdx.x;
  int wave = tid >> 6, lane = tid & 63;
  int lm = lane & 15, lq = lane >> 4;

  // --- phase 0: edge meta + spherical harmonics (f16)
  if (tid < EPB) {
    int eg = blockIdx.x * EPB + tid;
    int sa = 0, da = -1;
    float x = 0.f, y = 0.f, z = 0.f;
    if (eg < NE) {
      sa = eidx[eg];
      da = eidx[NE + eg];
      x = ev[3 * eg + 0]; y = ev[3 * eg + 1]; z = ev[3 * eg + 2];
    }
    sSrcA[tid] = sa;
    sDst[tid] = da;
    float x2 = x * x, y2 = y * y, z2 = z * z;
    float Y[16];
    Y[0]  = 0.28209479177387814f;
    Y[1]  = 0.4886025119029199f * y;
    Y[2]  = 0.4886025119029199f * z;
    Y[3]  = 0.4886025119029199f * x;
    Y[4]  = 1.0925484305920792f * x * y;
    Y[5]  = 1.0925484305920792f * y * z;
    Y[6]  = 0.31539156525252005f * (3.0f * z2 - 1.0f);
    Y[7]  = 1.0925484305920792f * x * z;
    Y[8]  = 0.5462742152960396f * (x2 - y2);
    Y[9]  = 0.5900435899266435f * y * (3.0f * x2 - y2);
    Y[10] = 2.890611442640554f * x * y * z;
    Y[11] = 0.4570457994644658f * y * (5.0f * z2 - 1.0f);
    Y[12] = 0.3731763325901154f * z * (5.0f * z2 - 3.0f);
    Y[13] = 0.4570457994644658f * x * (5.0f * z2 - 1.0f);
    Y[14] = 1.445305721320277f  * z * (x2 - y2);
    Y[15] = 0.5900435899266435f * x * (x2 - 3.0f * y2);
#pragma unroll
    for (int j = 0; j < 16; ++j) sYh[tid * 16 + j] = (f16)Y[j];
  }
  __syncthreads();

  // --- register-resident src fragments (coalesced float4 == MFMA B-layout)
  // 8 edges per wave: Sf[ei][hg] holds src[e][h=hg*16+lm][i=lq*4..+3]
  f16x4 Sf[8][4];
  int ebase = wave * 8;
#pragma unroll
  for (int ei = 0; ei < 8; ++ei) {
    const float4* src4 = (const float4*)nf + (size_t)sSrcA[ebase + ei] * 256;
#pragma unroll
    for (int hg = 0; hg < 4; ++hg) {
      float4 v = src4[(hg * 16 + lm) * 4 + lq];
      Sf[ei][hg] = f16x4{(f16)v.x, (f16)v.y, (f16)v.z, (f16)v.w};
    }
  }

  // B-frags for A-build: Y[e=lm][j] and Y[e=16+lm][j]
  f16x4 bY0 = *(const f16x4*)&sYh[lm * 16 + lq * 4];
  f16x4 bY1 = *(const f16x4*)&sYh[(16 + lm) * 16 + lq * 4];

  f32x4 acc[2][4];
#pragma unroll
  for (int et = 0; et < 2; ++et)
#pragma unroll
    for (int ot = 0; ot < 4; ++ot) acc[et][ot] = f32x4{0.f, 0.f, 0.f, 0.f};

  // A-build: NT_ tiles per wave starting at global kk = kkb_, both e-halves; D[row=i][col=e]
#define A_BUILD(kkb_, NT_)                                                             \
  {                                                                                    \
    _Pragma("unroll")                                                                  \
    for (int tl = 0; tl < (NT_); ++tl) {                                               \
      int t = wave * (NT_) + tl;                                                       \
      f16x4 aCG = *(const f16x4*)&CGd[(size_t)((kkb_) + t) * 256 + lm * 16 + lq * 4];  \
      f32x4 d0 = __builtin_amdgcn_mfma_f32_16x16x16f16(aCG, bY0, f32x4{0.f, 0.f, 0.f, 0.f}, 0, 0, 0); \
      f32x4 d1 = __builtin_amdgcn_mfma_f32_16x16x16f16(aCG, bY1, f32x4{0.f, 0.f, 0.f, 0.f}, 0, 0, 0); \
      f16x4 dh0 = {(f16)d0[0], (f16)d0[1], (f16)d0[2], (f16)d0[3]};                    \
      f16x4 dh1 = {(f16)d1[0], (f16)d1[1], (f16)d1[2], (f16)d1[3]};                    \
      *(f16x4*)&sA[lm * SA_ESTR + t * 16 + lq * 4] = dh0;        /* [e=lm   ][kk=t][i] */ \
      *(f16x4*)&sA[(16 + lm) * SA_ESTR + t * 16 + lq * 4] = dh1; /* [e=16+lm][kk=t][i] */ \
    }                                                                                  \
  }

  A_BUILD(0, 8);
  __syncthreads();

  // ================= full 32-kk tiles: kg = 0,1,2 =================
  for (int kg = 0; kg < 3; ++kg) {
#pragma unroll
    for (int hg = 0; hg < 4; ++hg) {
      // --- bF prefetch, first half (hi 0,1): 8 loads before GEMM-1, latency
      //     covered by GEMM-1 (champion pattern). Only 32 regs live through G1.
      f16x8 bFa[2][4];
#pragma unroll
      for (int hi2 = 0; hi2 < 2; ++hi2) {
        const f16* Fb = F + (size_t)(hg * 16 + wave + 4 * hi2) * 64 * NKPAD + kg * 32 + lq * 8;
#pragma unroll
        for (int ot = 0; ot < 4; ++ot)
          bFa[hi2][ot] = *(const f16x8*)&Fb[(size_t)(ot * 16 + lm) * NKPAD];
      }

      // --- GEMM-1: U[kk32][h'16] per edge; A=sA rows kkloc, B=Sf
#pragma unroll
      for (int ei = 0; ei < 8; ++ei) {
        int e = ebase + ei;
        f16x4 bS = Sf[ei][hg];
#pragma unroll
        for (int kt = 0; kt < 2; ++kt) {
          f16x4 aA = *(const f16x4*)&sA[e * SA_ESTR + (kt * 16 + lm) * 16 + lq * 4];
          f32x4 d = __builtin_amdgcn_mfma_f32_16x16x16f16(aA, bS, f32x4{0.f, 0.f, 0.f, 0.f}, 0, 0, 0);
          f16x4 dh = {(f16)d[0], (f16)d[1], (f16)d[2], (f16)d[3]};
          *(f16x4*)&sU[e * SU_ESTR + lm * SU_HSTR + kt * 16 + lq * 4] = dh;  // [e][h'=lm][kk]
        }
      }
      __syncthreads();

      // --- bF prefetch, second half (hi 2,3): issued here, consumed in G2's
      //     second half — covered by G2's first half (4 ds_read_b128 + 16 MFMA).
      f16x8 bFb[2][4];
#pragma unroll
      for (int hi2 = 0; hi2 < 2; ++hi2) {
        const f16* Fb = F + (size_t)(hg * 16 + wave + 4 * (hi2 + 2)) * 64 * NKPAD + kg * 32 + lq * 8;
#pragma unroll
        for (int ot = 0; ot < 4; ++ot)
          bFb[hi2][ot] = *(const f16x8*)&Fb[(size_t)(ot * 16 + lm) * NKPAD];
      }

      // --- GEMM-2 first half (hi 0,1) with bFa
#pragma unroll
      for (int hi = 0; hi < 2; ++hi) {
        int hl = wave + 4 * hi;
#pragma unroll
        for (int et = 0; et < 2; ++et) {
          f16x8 a0 = *(const f16x8*)&sU[(size_t)(et * 16 + lm) * SU_ESTR + hl * SU_HSTR + lq * 8];
#pragma unroll
          for (int ot = 0; ot < 4; ++ot)
            acc[et][ot] = __builtin_amdgcn_mfma_f32_16x16x32_f16(a0, bFa[hi][ot], acc[et][ot], 0, 0, 0);
        }
      }

      // --- GEMM-2 second half (hi 2,3) with bFb
#pragma unroll
      for (int hi = 0; hi < 2; ++hi) {
        int hl = wave + 4 * (hi + 2);
#pragma unroll
        for (int et = 0; et < 2; ++et) {
          f16x8 a0 = *(const f16x8*)&sU[(size_t)(et * 16 + lm) * SU_ESTR + hl * SU_HSTR + lq * 8];
#pragma unroll
          for (int ot = 0; ot < 4; ++ot)
            acc[et][ot] = __builtin_amdgcn_mfma_f32_16x16x32_f16(a0, bFb[hi][ot], acc[et][ot], 0, 0, 0);
        }
      }

      // --- A-build for the next kk-tile, AFTER G2 so bF VGPRs are dead before
      //     aCG/d0/d1 go live. Race-equivalent (sA writes sit between the mid-
      //     barrier retiring this kg's G1 reads and the end-barrier publishing
      //     for kg+1). sched_barrier(0) pins aCG loads out of bF's live range.
      if (hg == 3) {
        __builtin_amdgcn_sched_barrier(0);
        if (kg < 2) A_BUILD((kg + 1) * 32, 8)
        else        A_BUILD(96, 4)          // tail tile: 16 kk
      }
      __syncthreads();
    }
  }

  // ================= tail 16-kk tile: kk 96..111 (16x16x16 MFMA) =================
#pragma unroll
  for (int hg = 0; hg < 4; ++hg) {
    f16x4 bFt[4][4];
#pragma unroll
    for (int hi = 0; hi < 4; ++hi) {
      const f16* Fb = F + (size_t)(hg * 16 + wave + 4 * hi) * 64 * NKPAD + 96 + lq * 4;
#pragma unroll
      for (int ot = 0; ot < 4; ++ot)
        bFt[hi][ot] = *(const f16x4*)&Fb[(size_t)(ot * 16 + lm) * NKPAD];
    }

    // GEMM-1 tail: single 16-kk row block
#pragma unroll
    for (int ei = 0; ei < 8; ++ei) {
      int e = ebase + ei;
      f16x4 bS = Sf[ei][hg];
      f16x4 aA = *(const f16x4*)&sA[e * SA_ESTR + lm * 16 + lq * 4];
      f32x4 d = __builtin_amdgcn_mfma_f32_16x16x16f16(aA, bS, f32x4{0.f, 0.f, 0.f, 0.f}, 0, 0, 0);
      f16x4 dh = {(f16)d[0], (f16)d[1], (f16)d[2], (f16)d[3]};
      *(f16x4*)&sU[e * SU_ESTR + lm * SU_HSTR + lq * 4] = dh;
    }
    __syncthreads();

    // GEMM-2 tail: K = 16
#pragma unroll
    for (int hi = 0; hi < 4; ++hi) {
      int hl = wave + 4 * hi;
#pragma unroll
      for (int et = 0; et < 2; ++et) {
        f16x4 a0 = *(const f16x4*)&sU[(size_t)(et * 16 + lm) * SU_ESTR + hl * SU_HSTR + lq * 4];
#pragma unroll
        for (int ot = 0; ot < 4; ++ot)
          acc[et][ot] = __builtin_amdgcn_mfma_f32_16x16x16f16(a0, bFt[hi][ot], acc[et][ot], 0, 0, 0);
      }
    }
    __syncthreads();
  }

  // --- cross-wave reduction: red[wave][e][o2] (stride 68)
  float* red = (float*)sU;
#pragma unroll
  for (int et = 0; et < 2; ++et)
#pragma unroll
    for (int ot = 0; ot < 4; ++ot)
#pragma unroll
      for (int r = 0; r < 4; ++r) {
        int e = et * 16 + lq * 4 + r;    // D row
        int o2 = ot * 16 + lm;           // D col
        red[(wave * EPB + e) * RED_ESTR + o2] = acc[et][ot][r];
      }
  __syncthreads();

#pragma unroll
  for (int rep = 0; rep < 8; ++rep) {
    int idx = tid + rep * 256;           // 0..2047 = e*64+o2 ; e wave-uniform
    int e = idx >> 6, o2 = idx & 63;
    float s = red[(0 * EPB + e) * RED_ESTR + o2]
            + red[(1 * EPB + e) * RED_ESTR + o2]
            + red[(2 * EPB + e) * RED_ESTR + o2]
            + red[(3 * EPB + e) * RED_ESTR + o2];
    int da = sDst[e];
    if (da >= 0) unsafeAtomicAdd(out + (size_t)da * 64 + o2, s);
  }
}

extern "C" void kernel_launch(void* const* d_in, const int* in_sizes, int n_in,
                              void* d_out, int out_size, void* d_ws, size_t ws_size,
                              hipStream_t stream) {
  const float* nf   = (const float*)d_in[0];  // [NA,64,16]
  const float* ev   = (const float*)d_in[1];  // [NE,3]
  const int*   eidx = (const int*)d_in[2];    // [2,NE]
  const float* cg   = (const float*)d_in[3];  // [16,16,16]
  const float* tpw  = (const float*)d_in[4];  // [23,64,64]
  const float* wlin = (const float*)d_in[5];  // [64,1024]
  const float* blin = (const float*)d_in[6];  // [64]
  float* out = (float*)d_out;                 // [NA,64]

  int NA = in_sizes[0] / 1024;
  int NE = in_sizes[1] / 3;
  f16* F   = (f16*)d_ws;                                         // 64*64*112*2 = 896 KB
  f16* CGd = (f16*)((char*)d_ws + (size_t)64 * 64 * NKPAD * 2);  // 112*256*2 = 56 KB

  compute_F<<<NKPAD, 256, 0, stream>>>(tpw, wlin, cg, F, CGd);   // fused F + CGd (+pad zero)
  init_out<<<(NA * 64 + 255) / 256, 256, 0, stream>>>(out, blin, NA * 64);
  edge_kernel<<<(NE + EPB - 1) / EPB, THREADS, 0, stream>>>(nf, ev, eidx, CGd, F, out, NE);
}